// Round 6
// baseline (2045.734 us; speedup 1.0000x reference)
//
#include <hip/hip_runtime.h>
#include <hip/hip_bf16.h>
#include <math.h>

#define NF 128
#define EC 50
#define CUTOFF 0.8f
#define PI_F 3.14159265358979323846f

typedef __attribute__((ext_vector_type(8))) _Float16 f16x8;
typedef __attribute__((ext_vector_type(4))) float f32x4;

__device__ __forceinline__ float4 ld4(const float* p) { return *reinterpret_cast<const float4*>(p); }
__device__ __forceinline__ void st4(float* p, float4 v) { *reinterpret_cast<float4*>(p) = v; }

__device__ __forceinline__ float4 f4fma(float a, float4 w, float4 acc) {
    acc.x = fmaf(a, w.x, acc.x); acc.y = fmaf(a, w.y, acc.y);
    acc.z = fmaf(a, w.z, acc.z); acc.w = fmaf(a, w.w, acc.w);
    return acc;
}

__device__ __forceinline__ float sspf(float x) {
    return fmaxf(x, 0.0f) + log1pf(expf(-fabsf(x))) - 0.69314718055994530942f;
}
__device__ __forceinline__ float4 ssp4(float4 v) {
    v.x = sspf(v.x); v.y = sspf(v.y); v.z = sspf(v.z); v.w = sspf(v.w);
    return v;
}
__device__ __forceinline__ float swishf(float x) {
    return x / (1.0f + expf(-x));
}

// -------------------------------------------------------------------------
__global__ __launch_bounds__(256) void emb_kernel(const float* __restrict__ tt,
                                                  float* __restrict__ emb, int n) {
    int i = blockIdx.x * blockDim.x + threadIdx.x;
    if (i >= n * 64) return;
    int node = i >> 6, k = i & 63;
    float t = tt[node];
    float coef = expf((float)k * (-6.9077552789821368f / 63.0f));
    float e = t * coef;
    emb[node * NF + k]      = swishf(sinf(e));
    emb[node * NF + 64 + k] = swishf(cosf(e));
}

// -------------------------------------------------------------------------
// out[N,128] = f(A[N,128] @ W[128,128] (+bias) (+extra))
// MODE 0: plain. MODE 1: ssp(.+b). MODE 2: ssp(.+b+extra). MODE 3: .+b
// In-place safety: A==out is safe (A staged to LDS, barrier, then stores);
// extra==out is safe (each element read by the thread that writes it, before).
template<int MODE>
__global__ __launch_bounds__(256) void node_gemm(const float* A,
                                                 const float* __restrict__ W,
                                                 const float* __restrict__ bias,
                                                 const float* extra,
                                                 float* out, int n) {
    extern __shared__ float sm[];
    float* W_lds = sm;            // 128*128
    float* A_lds = sm + NF * NF;  // 32*128
    const int tid = threadIdx.x;
    const int cg = tid & 31;
    const int rg = tid >> 5;

    for (int idx = tid * 4; idx < NF * NF; idx += 1024)
        st4(W_lds + idx, ld4(W + idx));

    float4 bv = make_float4(0.f, 0.f, 0.f, 0.f);
    if (MODE != 0) bv = ld4(bias + 4 * cg);

    const int ntile = (n + 31) >> 5;
    for (int tile = blockIdx.x; tile < ntile; tile += gridDim.x) {
        const int base = tile << 5;
        __syncthreads();
        for (int idx = tid * 4; idx < 32 * NF; idx += 1024) {
            int r = idx >> 7;
            int row = base + r;
            float4 v = make_float4(0.f, 0.f, 0.f, 0.f);
            if (row < n) v = ld4(A + row * NF + (idx & 127));
            st4(A_lds + idx, v);
        }
        __syncthreads();

        float4 acc[4] = {bv, bv, bv, bv};
        #pragma unroll 8
        for (int k4 = 0; k4 < 32; k4++) {
            float4 w0 = ld4(W_lds + (4 * k4 + 0) * NF + 4 * cg);
            float4 w1 = ld4(W_lds + (4 * k4 + 1) * NF + 4 * cg);
            float4 w2 = ld4(W_lds + (4 * k4 + 2) * NF + 4 * cg);
            float4 w3 = ld4(W_lds + (4 * k4 + 3) * NF + 4 * cg);
            #pragma unroll
            for (int rr = 0; rr < 4; rr++) {
                float4 a = ld4(A_lds + (rg * 4 + rr) * NF + 4 * k4);
                acc[rr] = f4fma(a.x, w0, acc[rr]);
                acc[rr] = f4fma(a.y, w1, acc[rr]);
                acc[rr] = f4fma(a.z, w2, acc[rr]);
                acc[rr] = f4fma(a.w, w3, acc[rr]);
            }
        }
        #pragma unroll
        for (int rr = 0; rr < 4; rr++) {
            int row = base + rg * 4 + rr;
            if (row >= n) continue;
            float4 v = acc[rr];
            if (MODE == 2) {
                float4 e4 = ld4(extra + row * NF + 4 * cg);
                v.x += e4.x; v.y += e4.y; v.z += e4.z; v.w += e4.w;
            }
            if (MODE == 1 || MODE == 2) v = ssp4(v);
            st4(out + row * NF + 4 * cg, v);
        }
    }
}

// -------------------------------------------------------------------------
// CSR build
__global__ __launch_bounds__(256) void deg_kernel(const int* __restrict__ ei,
                                                  int* __restrict__ deg, int E_) {
    int e = blockIdx.x * blockDim.x + threadIdx.x;
    if (e < E_) atomicAdd(&deg[ei[E_ + e]], 1);
}

__global__ __launch_bounds__(1024) void scan_kernel(const int* __restrict__ deg,
                                                    int* __restrict__ off, int n) {
    __shared__ int sm[1024];
    __shared__ int carry_s;
    const int tid = threadIdx.x;
    if (tid == 0) carry_s = 0;
    __syncthreads();
    for (int base = 0; base < n; base += 1024) {
        int v = (base + tid < n) ? deg[base + tid] : 0;
        sm[tid] = v;
        __syncthreads();
        for (int s = 1; s < 1024; s <<= 1) {
            int t = (tid >= s) ? sm[tid - s] : 0;
            __syncthreads();
            sm[tid] += t;
            __syncthreads();
        }
        int carry = carry_s;
        if (base + tid < n) off[base + tid] = carry + sm[tid] - v;  // exclusive
        __syncthreads();
        if (tid == 0) carry_s = carry + sm[1023];
        __syncthreads();
    }
    if (tid == 0) off[n] = carry_s;
}

__global__ __launch_bounds__(256) void scatter_kernel(const int* __restrict__ ei,
                                                      const int* __restrict__ off,
                                                      int* __restrict__ cur,
                                                      int* __restrict__ perm, int E_) {
    int e = blockIdx.x * blockDim.x + threadIdx.x;
    if (e < E_) {
        int d = ei[E_ + e];
        int p = off[d] + atomicAdd(&cur[d], 1);
        perm[p] = e;
    }
}

// -------------------------------------------------------------------------
// Node-centric cfconv, zero f32 atomics. Pad slots fully zeroed (ea row = 0,
// C = 0, src = 0). ea staging is R3's exact scalar pattern.
__global__ __launch_bounds__(256, 3) void node_conv(const float* __restrict__ y,
                                                    const int* __restrict__ ei,
                                                    const float* __restrict__ elen,
                                                    const float* __restrict__ eattr,
                                                    const float* __restrict__ em1w,
                                                    const float* __restrict__ em1b,
                                                    const float* __restrict__ em2w,
                                                    const float* __restrict__ em2b,
                                                    const int* __restrict__ off,
                                                    const int* __restrict__ perm,
                                                    float* __restrict__ agg,
                                                    int nN, int E_) {
    __shared__ __align__(16) char ea_b[16 * 128];   // [16 edges][64 k] fp16, swizzled
    __shared__ __align__(16) char h_b[16 * 256];    // [16 edges][128 ch] fp16, swizzled
    __shared__ float C_sm[16];
    __shared__ int ss[16];

    const int tid  = threadIdx.x;
    const int wid  = tid >> 6;
    const int lane = tid & 63;
    const int l15  = lane & 15;
    const int lhi  = lane >> 4;

    // ---- preload weight B-frags (R3-verified layout)
    f16x8 w1f[2][2];
    f16x8 w2f[2][4];
    float b1c[2], b2c[2];
    #pragma unroll
    for (int ct = 0; ct < 2; ct++) {
        const int col = (2 * wid + ct) * 16 + l15;
        b1c[ct] = em1b[col];
        b2c[ct] = em2b[col];
        #pragma unroll
        for (int t = 0; t < 2; t++)
            #pragma unroll
            for (int j = 0; j < 8; j++) {
                int k = t * 32 + lhi * 8 + j;
                w1f[ct][t][j] = (_Float16)((k < EC) ? em1w[k * NF + col] : 0.0f);
            }
        #pragma unroll
        for (int t = 0; t < 4; t++)
            #pragma unroll
            for (int j = 0; j < 8; j++) {
                int k = t * 32 + lhi * 8 + j;
                w2f[ct][t][j] = (_Float16)em2w[k * NF + col];
            }
    }

    for (int n0 = blockIdx.x; n0 < nN; n0 += gridDim.x) {
        const int s0 = off[n0], s1 = off[n0 + 1];
        const int ntile = (s1 - s0 + 15) >> 4;
        float nacc[2] = {0.0f, 0.0f};

        for (int t = 0; t < ntile; t++) {
            __syncthreads();
            // ---- meta: C, src per edge slot (pads: C=0, src=0)
            if (tid < 16) {
                int ii = s0 + t * 16 + tid;
                float Cv = 0.0f; int s = 0;
                if (ii < s1) {
                    int e = perm[ii];
                    s = ei[e];
                    float len = elen[e];
                    float c = 0.5f * (cosf(len * (PI_F / CUTOFF)) + 1.0f);
                    Cv = (len <= CUTOFF && len >= 0.0f) ? c : 0.0f;
                }
                C_sm[tid] = Cv; ss[tid] = s;
            }
            // ---- stage ea tile, scalar stores (R3 pattern); pads zeroed
            for (int idx = tid; idx < 16 * 64; idx += 256) {
                int row = idx >> 6, k = idx & 63;
                int ii = s0 + t * 16 + row;
                float v = 0.0f;
                if (ii < s1 && k < EC)
                    v = eattr[(size_t)perm[ii] * EC + k];
                int o = row * 128 + ((2 * k) ^ ((row & 7) << 4));
                *(_Float16*)(ea_b + o) = (_Float16)v;
            }
            __syncthreads();

            // ---- layer 1: h = ssp(ea @ em1 + b1)
            f32x4 a1[2];
            #pragma unroll
            for (int ct = 0; ct < 2; ct++) {
                f32x4 b = {b1c[ct], b1c[ct], b1c[ct], b1c[ct]};
                a1[ct] = b;
            }
            #pragma unroll
            for (int t1 = 0; t1 < 2; t1++) {
                int o = l15 * 128 + ((t1 * 64 + lhi * 16) ^ ((l15 & 7) << 4));
                f16x8 a = *(const f16x8*)(ea_b + o);
                #pragma unroll
                for (int ct = 0; ct < 2; ct++)
                    a1[ct] = __builtin_amdgcn_mfma_f32_16x16x32_f16(a, w1f[ct][t1], a1[ct], 0, 0, 0);
            }
            #pragma unroll
            for (int ct = 0; ct < 2; ct++) {
                const int col = (2 * wid + ct) * 16 + l15;
                #pragma unroll
                for (int r = 0; r < 4; r++) {
                    int row = lhi * 4 + r;
                    *(_Float16*)(h_b + row * 256 + ((2 * col) ^ ((row & 7) << 4))) =
                        (_Float16)sspf(a1[ct][r]);
                }
            }
            __syncthreads();

            // ---- layer 2 + gather + in-register reduce
            float Cr[4]; int sr[4];
            #pragma unroll
            for (int r = 0; r < 4; r++) { Cr[r] = C_sm[lhi * 4 + r]; sr[r] = ss[lhi * 4 + r]; }
            float yv[2][4];
            #pragma unroll
            for (int ct = 0; ct < 2; ct++)
                #pragma unroll
                for (int r = 0; r < 4; r++)
                    yv[ct][r] = y[(size_t)sr[r] * NF + (2 * wid + ct) * 16 + l15];

            f32x4 a2[2];
            #pragma unroll
            for (int ct = 0; ct < 2; ct++) {
                f32x4 b = {b2c[ct], b2c[ct], b2c[ct], b2c[ct]};
                a2[ct] = b;
            }
            #pragma unroll
            for (int t2 = 0; t2 < 4; t2++) {
                int o = l15 * 256 + ((t2 * 64 + lhi * 16) ^ ((l15 & 7) << 4));
                f16x8 a = *(const f16x8*)(h_b + o);
                #pragma unroll
                for (int ct = 0; ct < 2; ct++)
                    a2[ct] = __builtin_amdgcn_mfma_f32_16x16x32_f16(a, w2f[ct][t2], a2[ct], 0, 0, 0);
            }
            #pragma unroll
            for (int ct = 0; ct < 2; ct++)
                #pragma unroll
                for (int r = 0; r < 4; r++)
                    nacc[ct] = fmaf(a2[ct][r] * Cr[r], yv[ct][r], nacc[ct]);
        }

        #pragma unroll
        for (int ct = 0; ct < 2; ct++) {
            float v = nacc[ct];
            v += __shfl_xor(v, 16);
            v += __shfl_xor(v, 32);
            if (lhi == 0)
                agg[(size_t)n0 * NF + (2 * wid + ct) * 16 + l15] = v;
        }
    }
}

// -------------------------------------------------------------------------
extern "C" void kernel_launch(void* const* d_in, const int* in_sizes, int n_in,
                              void* d_out, int out_size, void* d_ws, size_t ws_size,
                              hipStream_t stream) {
    const float* tt    = (const float*)d_in[0];
    const float* xx    = (const float*)d_in[1];
    const int*   ei    = (const int*)d_in[2];
    const float* elen  = (const float*)d_in[3];
    const float* eattr = (const float*)d_in[4];
    const float* em1w  = (const float*)d_in[5];
    const float* em1b  = (const float*)d_in[6];
    const float* em2w  = (const float*)d_in[7];
    const float* em2b  = (const float*)d_in[8];
    const float* c1m1w = (const float*)d_in[9];
    const float* c1m2w = (const float*)d_in[10];
    const float* c1m2b = (const float*)d_in[11];
    const float* c2m1w = (const float*)d_in[12];
    const float* c2m2w = (const float*)d_in[13];
    const float* c2m2b = (const float*)d_in[14];
    const float* tew   = (const float*)d_in[15];
    const float* teb   = (const float*)d_in[16];
    const float* linw  = (const float*)d_in[17];
    const float* linb  = (const float*)d_in[18];

    const int n  = in_sizes[0];
    const int E_ = in_sizes[2] / 2;
    float* out = (float*)d_out;

    // ws: B0,B1,B2 (3*NB floats) + CSR ints. No d_out aliasing anywhere.
    const size_t NB = (size_t)n * NF;
    float* B0 = (float*)d_ws;   // y1 / y2 / x3
    float* B1 = B0 + NB;        // agg
    float* B2 = B1 + NB;        // emb -> t (in-place) -> x_mid (extra==out safe)
    int* off  = (int*)(B2 + NB);
    int* perm = off + (n + 1);
    int* deg  = perm + E_;
    int* cur  = deg + n;

    const size_t gemm_shmem = (size_t)(NF * NF + 32 * NF) * sizeof(float);   // 80 KB

    // ---- CSR build (shared by both convs)
    hipMemsetAsync(deg, 0, (size_t)2 * n * sizeof(int), stream);
    deg_kernel<<<(E_ + 255) / 256, 256, 0, stream>>>(ei, deg, E_);
    scan_kernel<<<1, 1024, 0, stream>>>(deg, off, n);
    scatter_kernel<<<(E_ + 255) / 256, 256, 0, stream>>>(ei, off, cur, perm, E_);

    // emb -> B2 ; t = swish_emb @ te_w + te_b -> B2 (in-place, barrier-staged)
    emb_kernel<<<(n * 64 + 255) / 256, 256, 0, stream>>>(tt, B2, n);
    node_gemm<3><<<512, 256, gemm_shmem, stream>>>(B2, tew, teb, nullptr, B2, n);

    // y1 = xx @ c1_m1w -> B0
    node_gemm<0><<<512, 256, gemm_shmem, stream>>>(xx, c1m1w, nullptr, nullptr, B0, n);

    // conv1 -> B1
    node_conv<<<1024, 256, 0, stream>>>(B0, ei, elen, eattr,
                                        em1w, em1b, em2w, em2b, off, perm, B1, n, E_);

    // x_mid = ssp(agg @ c1_m2w + b + t) -> B2 (extra==out elementwise-safe)
    node_gemm<2><<<512, 256, gemm_shmem, stream>>>(B1, c1m2w, c1m2b, B2, B2, n);

    // y2 = x_mid @ c2_m1w -> B0
    node_gemm<0><<<512, 256, gemm_shmem, stream>>>(B2, c2m1w, nullptr, nullptr, B0, n);

    // conv2 -> B1
    node_conv<<<1024, 256, 0, stream>>>(B0, ei, elen, eattr,
                                        em1w, em1b, em2w, em2b, off, perm, B1, n, E_);

    // x3 = ssp(agg @ c2_m2w + b) -> B0 ; out = ssp(x3 @ lin_w + b) -> d_out
    node_gemm<1><<<512, 256, gemm_shmem, stream>>>(B1, c2m2w, c2m2b, nullptr, B0, n);
    node_gemm<1><<<512, 256, gemm_shmem, stream>>>(B0, linw, linb, nullptr, out, n);
}

// Round 7
// 1216.360 us; speedup vs baseline: 1.6818x; 1.6818x over previous
//
#include <hip/hip_runtime.h>
#include <hip/hip_bf16.h>
#include <math.h>

#define NF 128
#define EC 50
#define ET 64              // edges per seg_conv tile
#define CUTOFF 0.8f
#define PI_F 3.14159265358979323846f

typedef __attribute__((ext_vector_type(8))) _Float16 f16x8;
typedef __attribute__((ext_vector_type(2))) _Float16 f16x2;
typedef __attribute__((ext_vector_type(4))) float f32x4;

__device__ __forceinline__ float4 ld4(const float* p) { return *reinterpret_cast<const float4*>(p); }
__device__ __forceinline__ void st4(float* p, float4 v) { *reinterpret_cast<float4*>(p) = v; }

__device__ __forceinline__ float4 f4fma(float a, float4 w, float4 acc) {
    acc.x = fmaf(a, w.x, acc.x); acc.y = fmaf(a, w.y, acc.y);
    acc.z = fmaf(a, w.z, acc.z); acc.w = fmaf(a, w.w, acc.w);
    return acc;
}

// fast ssp: hardware exp/log (v_exp_f32/v_log_f32); abs err ~1e-7, fine vs 2.3e-2 threshold
__device__ __forceinline__ float sspf(float x) {
    return fmaxf(x, 0.0f) + __logf(1.0f + __expf(-fabsf(x))) - 0.69314718055994530942f;
}
__device__ __forceinline__ float4 ssp4(float4 v) {
    v.x = sspf(v.x); v.y = sspf(v.y); v.z = sspf(v.z); v.w = sspf(v.w);
    return v;
}
__device__ __forceinline__ float swishf(float x) {
    return x / (1.0f + __expf(-x));
}

// -------------------------------------------------------------------------
__global__ __launch_bounds__(256) void emb_kernel(const float* __restrict__ tt,
                                                  float* __restrict__ emb, int n) {
    int i = blockIdx.x * blockDim.x + threadIdx.x;
    if (i >= n * 64) return;
    int node = i >> 6, k = i & 63;
    float t = tt[node];
    float coef = __expf((float)k * (-6.9077552789821368f / 63.0f));
    float e = t * coef;
    emb[node * NF + k]      = swishf(sinf(e));
    emb[node * NF + 64 + k] = swishf(cosf(e));
}

// -------------------------------------------------------------------------
// out[N,128] = f(A[N,128] @ W[128,128] (+bias) (+extra))
// MODE 0: plain. MODE 1: ssp(.+b). MODE 2: ssp(.+b+extra). MODE 3: .+b
// In-place safety: A==out safe (A staged to LDS before stores); extra==out
// safe (each element read by its writing thread before the write).
template<int MODE>
__global__ __launch_bounds__(256) void node_gemm(const float* A,
                                                 const float* __restrict__ W,
                                                 const float* __restrict__ bias,
                                                 const float* extra,
                                                 float* out, int n) {
    extern __shared__ float sm[];
    float* W_lds = sm;            // 128*128
    float* A_lds = sm + NF * NF;  // 32*128
    const int tid = threadIdx.x;
    const int cg = tid & 31;
    const int rg = tid >> 5;

    for (int idx = tid * 4; idx < NF * NF; idx += 1024)
        st4(W_lds + idx, ld4(W + idx));

    float4 bv = make_float4(0.f, 0.f, 0.f, 0.f);
    if (MODE != 0) bv = ld4(bias + 4 * cg);

    const int ntile = (n + 31) >> 5;
    for (int tile = blockIdx.x; tile < ntile; tile += gridDim.x) {
        const int base = tile << 5;
        __syncthreads();
        for (int idx = tid * 4; idx < 32 * NF; idx += 1024) {
            int r = idx >> 7;
            int row = base + r;
            float4 v = make_float4(0.f, 0.f, 0.f, 0.f);
            if (row < n) v = ld4(A + row * NF + (idx & 127));
            st4(A_lds + idx, v);
        }
        __syncthreads();

        float4 acc[4] = {bv, bv, bv, bv};
        #pragma unroll 8
        for (int k4 = 0; k4 < 32; k4++) {
            float4 w0 = ld4(W_lds + (4 * k4 + 0) * NF + 4 * cg);
            float4 w1 = ld4(W_lds + (4 * k4 + 1) * NF + 4 * cg);
            float4 w2 = ld4(W_lds + (4 * k4 + 2) * NF + 4 * cg);
            float4 w3 = ld4(W_lds + (4 * k4 + 3) * NF + 4 * cg);
            #pragma unroll
            for (int rr = 0; rr < 4; rr++) {
                float4 a = ld4(A_lds + (rg * 4 + rr) * NF + 4 * k4);
                acc[rr] = f4fma(a.x, w0, acc[rr]);
                acc[rr] = f4fma(a.y, w1, acc[rr]);
                acc[rr] = f4fma(a.z, w2, acc[rr]);
                acc[rr] = f4fma(a.w, w3, acc[rr]);
            }
        }
        #pragma unroll
        for (int rr = 0; rr < 4; rr++) {
            int row = base + rg * 4 + rr;
            if (row >= n) continue;
            float4 v = acc[rr];
            if (MODE == 2) {
                float4 e4 = ld4(extra + row * NF + 4 * cg);
                v.x += e4.x; v.y += e4.y; v.z += e4.z; v.w += e4.w;
            }
            if (MODE == 1 || MODE == 2) v = ssp4(v);
            st4(out + row * NF + 4 * cg, v);
        }
    }
}

// -------------------------------------------------------------------------
// CSR build (proven in R6)
__global__ __launch_bounds__(256) void deg_kernel(const int* __restrict__ ei,
                                                  int* __restrict__ deg, int E_) {
    int e = blockIdx.x * blockDim.x + threadIdx.x;
    if (e < E_) atomicAdd(&deg[ei[E_ + e]], 1);
}

__global__ __launch_bounds__(1024) void scan_kernel(const int* __restrict__ deg,
                                                    int* __restrict__ off, int n) {
    __shared__ int sm[1024];
    __shared__ int carry_s;
    const int tid = threadIdx.x;
    if (tid == 0) carry_s = 0;
    __syncthreads();
    for (int base = 0; base < n; base += 1024) {
        int v = (base + tid < n) ? deg[base + tid] : 0;
        sm[tid] = v;
        __syncthreads();
        for (int s = 1; s < 1024; s <<= 1) {
            int t = (tid >= s) ? sm[tid - s] : 0;
            __syncthreads();
            sm[tid] += t;
            __syncthreads();
        }
        int carry = carry_s;
        if (base + tid < n) off[base + tid] = carry + sm[tid] - v;  // exclusive
        __syncthreads();
        if (tid == 0) carry_s = carry + sm[1023];
        __syncthreads();
    }
    if (tid == 0) off[n] = carry_s;
}

__global__ __launch_bounds__(256) void scatter_kernel(const int* __restrict__ ei,
                                                      const int* __restrict__ off,
                                                      int* __restrict__ cur,
                                                      int* __restrict__ perm, int E_) {
    int e = blockIdx.x * blockDim.x + threadIdx.x;
    if (e < E_) {
        int d = ei[E_ + e];
        int p = off[d] + atomicAdd(&cur[d], 1);
        perm[p] = e;
    }
}

// -------------------------------------------------------------------------
// Edge-centric cfconv over dst-sorted edges, 64-edge dense MFMA tiles,
// in-tile segmented reduction (LDS msg -> coalesced y -> few atomics).
__global__ __launch_bounds__(256, 4) void seg_conv(const float* __restrict__ y,
                                                   const int* __restrict__ ei,
                                                   const float* __restrict__ elen,
                                                   const float* __restrict__ eattr,
                                                   const float* __restrict__ em1w,
                                                   const float* __restrict__ em1b,
                                                   const float* __restrict__ em2w,
                                                   const float* __restrict__ em2b,
                                                   const int* __restrict__ perm,
                                                   float* __restrict__ agg,
                                                   int E_) {
    // union region: [ea 8KB | h 16KB] overlapped by msg (33792 B)
    __shared__ __align__(16) char U[ET * 132 * 4];
    __shared__ float C_sm[ET];
    __shared__ int ss[ET];
    __shared__ int dd[ET];
    char* ea_p = U;               // [64][64k] fp16 swizzled
    char* h_p  = U + ET * 128;    // [64][128ch] fp16 swizzled
    float* msg = (float*)U;       // [64][132] f32

    const int tid  = threadIdx.x;
    const int wid  = tid >> 6;
    const int lane = tid & 63;
    const int l15  = lane & 15;
    const int lhi  = lane >> 4;

    // ---- preload weight B-frags (R3-verified layout)
    f16x8 w1f[2][2];
    f16x8 w2f[2][4];
    float b1c[2], b2c[2];
    #pragma unroll
    for (int ct = 0; ct < 2; ct++) {
        const int col = (2 * wid + ct) * 16 + l15;
        b1c[ct] = em1b[col];
        b2c[ct] = em2b[col];
        #pragma unroll
        for (int t = 0; t < 2; t++)
            #pragma unroll
            for (int j = 0; j < 8; j++) {
                int k = t * 32 + lhi * 8 + j;
                w1f[ct][t][j] = (_Float16)((k < EC) ? em1w[k * NF + col] : 0.0f);
            }
        #pragma unroll
        for (int t = 0; t < 4; t++)
            #pragma unroll
            for (int j = 0; j < 8; j++) {
                int k = t * 32 + lhi * 8 + j;
                w2f[ct][t][j] = (_Float16)em2w[k * NF + col];
            }
    }

    const int ntiles = (E_ + ET - 1) / ET;
    for (int tile = blockIdx.x; tile < ntiles; tile += gridDim.x) {
        const int base = tile * ET;
        __syncthreads();   // prev reduce done; safe to overwrite U/meta

        // ---- meta: C, src, dst per slot (pads: 0/0/0)
        if (tid < ET) {
            int ii = base + tid;
            float Cv = 0.0f; int s = 0, d = 0;
            if (ii < E_) {
                int e = perm[ii];
                s = ei[e]; d = ei[E_ + e];
                float len = elen[e];
                float c = 0.5f * (cosf(len * (PI_F / CUTOFF)) + 1.0f);
                Cv = (len <= CUTOFF && len >= 0.0f) ? c : 0.0f;
            }
            C_sm[tid] = Cv; ss[tid] = s; dd[tid] = d;
        }
        // ---- stage ea: thread -> (row = tid>>2, 16 k's); float2 loads
        // (aligned: 200*e + 4k, k even => 8-aligned), packed b32 LDS stores
        {
            int row = tid >> 2, part = tid & 3;
            int ii = base + row;
            bool val = ii < E_;
            const float* ep = eattr + (size_t)(val ? perm[ii] : 0) * EC;
            #pragma unroll
            for (int kk = 0; kk < 16; kk += 2) {
                int k = part * 16 + kk;
                float2 v = make_float2(0.f, 0.f);
                if (val && k <= 48) v = *(const float2*)(ep + k);
                f16x2 p;
                p[0] = (_Float16)v.x; p[1] = (_Float16)v.y;
                *(f16x2*)(ea_p + row * 128 + ((2 * k) ^ ((row & 7) << 4))) = p;
            }
        }
        __syncthreads();

        // ---- layer 1: h = ssp(ea @ em1 + b1)   (R3-verified)
        f32x4 acc[4][2];
        #pragma unroll
        for (int m = 0; m < 4; m++)
            #pragma unroll
            for (int ct = 0; ct < 2; ct++) {
                f32x4 b = {b1c[ct], b1c[ct], b1c[ct], b1c[ct]};
                acc[m][ct] = b;
            }
        #pragma unroll
        for (int m = 0; m < 4; m++) {
            const int row = m * 16 + l15;
            #pragma unroll
            for (int t1 = 0; t1 < 2; t1++) {
                int o = row * 128 + ((t1 * 64 + lhi * 16) ^ ((row & 7) << 4));
                f16x8 a = *(const f16x8*)(ea_p + o);
                #pragma unroll
                for (int ct = 0; ct < 2; ct++)
                    acc[m][ct] = __builtin_amdgcn_mfma_f32_16x16x32_f16(a, w1f[ct][t1], acc[m][ct], 0, 0, 0);
            }
        }
        #pragma unroll
        for (int m = 0; m < 4; m++)
            #pragma unroll
            for (int ct = 0; ct < 2; ct++) {
                const int col = (2 * wid + ct) * 16 + l15;
                #pragma unroll
                for (int r = 0; r < 4; r++) {
                    int row = m * 16 + lhi * 4 + r;
                    *(_Float16*)(h_p + row * 256 + ((2 * col) ^ ((row & 7) << 4))) =
                        (_Float16)sspf(acc[m][ct][r]);
                }
            }
        __syncthreads();

        // ---- layer 2: wf = h @ em2 + b2   (R3-verified)
        #pragma unroll
        for (int m = 0; m < 4; m++)
            #pragma unroll
            for (int ct = 0; ct < 2; ct++) {
                f32x4 b = {b2c[ct], b2c[ct], b2c[ct], b2c[ct]};
                acc[m][ct] = b;
            }
        #pragma unroll
        for (int m = 0; m < 4; m++) {
            const int row = m * 16 + l15;
            #pragma unroll
            for (int t2 = 0; t2 < 4; t2++) {
                int o = row * 256 + ((t2 * 64 + lhi * 16) ^ ((row & 7) << 4));
                f16x8 a = *(const f16x8*)(h_p + o);
                #pragma unroll
                for (int ct = 0; ct < 2; ct++)
                    acc[m][ct] = __builtin_amdgcn_mfma_f32_16x16x32_f16(a, w2f[ct][t2], acc[m][ct], 0, 0, 0);
            }
        }
        __syncthreads();   // all h reads done; msg may overwrite ea/h

        // ---- msg[e][ch] = wf * C  (row stride 132 -> conflict-free)
        #pragma unroll
        for (int m = 0; m < 4; m++)
            #pragma unroll
            for (int ct = 0; ct < 2; ct++) {
                #pragma unroll
                for (int r = 0; r < 4; r++) {
                    int e = m * 16 + lhi * 4 + r;
                    int ch = (2 * wid + ct) * 16 + l15;
                    msg[e * 132 + ch] = acc[m][ct][r] * C_sm[e];
                }
            }
        __syncthreads();

        // ---- segmented reduce: thread = (channel, 32-edge half)
        {
            int ch = tid >> 1, eh = tid & 1;
            float a = 0.0f;
            int prev = dd[eh * 32];
            #pragma unroll 8
            for (int q = 0; q < 32; q++) {
                int e = eh * 32 + q;
                int d = dd[e];
                float v = msg[e * 132 + ch] * y[(size_t)ss[e] * NF + ch];
                if (d != prev) {
                    unsafeAtomicAdd(agg + (size_t)prev * NF + ch, a);
                    a = 0.0f; prev = d;
                }
                a += v;
            }
            unsafeAtomicAdd(agg + (size_t)prev * NF + ch, a);
        }
    }
}

// -------------------------------------------------------------------------
extern "C" void kernel_launch(void* const* d_in, const int* in_sizes, int n_in,
                              void* d_out, int out_size, void* d_ws, size_t ws_size,
                              hipStream_t stream) {
    const float* tt    = (const float*)d_in[0];
    const float* xx    = (const float*)d_in[1];
    const int*   ei    = (const int*)d_in[2];
    const float* elen  = (const float*)d_in[3];
    const float* eattr = (const float*)d_in[4];
    const float* em1w  = (const float*)d_in[5];
    const float* em1b  = (const float*)d_in[6];
    const float* em2w  = (const float*)d_in[7];
    const float* em2b  = (const float*)d_in[8];
    const float* c1m1w = (const float*)d_in[9];
    const float* c1m2w = (const float*)d_in[10];
    const float* c1m2b = (const float*)d_in[11];
    const float* c2m1w = (const float*)d_in[12];
    const float* c2m2w = (const float*)d_in[13];
    const float* c2m2b = (const float*)d_in[14];
    const float* tew   = (const float*)d_in[15];
    const float* teb   = (const float*)d_in[16];
    const float* linw  = (const float*)d_in[17];
    const float* linb  = (const float*)d_in[18];

    const int n  = in_sizes[0];
    const int E_ = in_sizes[2] / 2;
    float* out = (float*)d_out;

    // ws: B0,B1,B2 (3*NB floats) + CSR ints. No d_out aliasing.
    const size_t NB = (size_t)n * NF;
    float* B0 = (float*)d_ws;   // y1 / y2 / x3
    float* B1 = B0 + NB;        // agg
    float* B2 = B1 + NB;        // emb -> t (in-place) -> x_mid
    int* off  = (int*)(B2 + NB);
    int* perm = off + (n + 1);
    int* deg  = perm + E_;
    int* cur  = deg + n;

    const size_t gemm_shmem = (size_t)(NF * NF + 32 * NF) * sizeof(float);   // 80 KB

    // ---- CSR build (shared by both convs)
    hipMemsetAsync(deg, 0, (size_t)2 * n * sizeof(int), stream);
    deg_kernel<<<(E_ + 255) / 256, 256, 0, stream>>>(ei, deg, E_);
    scan_kernel<<<1, 1024, 0, stream>>>(deg, off, n);
    scatter_kernel<<<(E_ + 255) / 256, 256, 0, stream>>>(ei, off, cur, perm, E_);

    // emb -> B2 ; t = swish_emb @ te_w + te_b -> B2 (in-place safe)
    emb_kernel<<<(n * 64 + 255) / 256, 256, 0, stream>>>(tt, B2, n);
    node_gemm<3><<<512, 256, gemm_shmem, stream>>>(B2, tew, teb, nullptr, B2, n);

    // y1 = xx @ c1_m1w -> B0
    node_gemm<0><<<512, 256, gemm_shmem, stream>>>(xx, c1m1w, nullptr, nullptr, B0, n);

    // conv1 -> B1 (atomic-accumulated; zero first)
    hipMemsetAsync(B1, 0, NB * sizeof(float), stream);
    seg_conv<<<1024, 256, 0, stream>>>(B0, ei, elen, eattr,
                                       em1w, em1b, em2w, em2b, perm, B1, E_);

    // x_mid = ssp(agg @ c1_m2w + b + t) -> B2 (extra==out elementwise-safe)
    node_gemm<2><<<512, 256, gemm_shmem, stream>>>(B1, c1m2w, c1m2b, B2, B2, n);

    // y2 = x_mid @ c2_m1w -> B0
    node_gemm<0><<<512, 256, gemm_shmem, stream>>>(B2, c2m1w, nullptr, nullptr, B0, n);

    // conv2 -> B1
    hipMemsetAsync(B1, 0, NB * sizeof(float), stream);
    seg_conv<<<1024, 256, 0, stream>>>(B0, ei, elen, eattr,
                                       em1w, em1b, em2w, em2b, perm, B1, E_);

    // x3 = ssp(agg @ c2_m2w + b) -> B0 ; out = ssp(x3 @ lin_w + b) -> d_out
    node_gemm<1><<<512, 256, gemm_shmem, stream>>>(B1, c2m2w, c2m2b, nullptr, B0, n);
    node_gemm<1><<<512, 256, gemm_shmem, stream>>>(B0, linw, linb, nullptr, out, n);
}